// Round 5
// baseline (167.460 us; speedup 1.0000x reference)
//
#include <hip/hip_runtime.h>

// PointSample: bilinear grid sample, zero border.
// features: (8,128,128,256) f32, grid: (8,16384,2) f32, out: (8,16384,256) f32.
//
// Locality-bucketed version: points are count-sorted into 128 buckets
// (8 batches x 16 tiles of 32x32 px, tile = 1 MB of features) via
// histogram -> prefix-scan -> scatter, then the main kernel processes
// points bucket-major with an XCD-chunked block swizzle (each XCD walks
// one batch, one tile at a time resident in its 4 MiB L2). This targets
// the measured 87 MB of HBM re-fetch (222 MB vs 135 ideal) and the
// L2-miss latency of random gathers.

constexpr int B = 8, H = 128, W = 128, C = 256, P = 16384;
constexpr int PPW = 4;                  // points per wave (main kernel)
constexpr int TS = 32;                  // tile edge in pixels
constexpr int TPS = W / TS;             // 4 tiles per side
constexpr int TPB = TPS * TPS;          // 16 tiles per batch
constexpr int NT = B * TPB;             // 128 buckets
constexpr int NPTS = B * P;             // 131072 points
constexpr int NBLK = NPTS / (4 * PPW);  // 8192 main-kernel blocks

typedef float f32x4 __attribute__((ext_vector_type(4)));

__device__ __forceinline__ int tile_of(int pt, const float* grid) {
    const int b = pt >> 14;
    const float gx = grid[2 * pt + 0];
    const float gy = grid[2 * pt + 1];
    int ix = (int)floorf(gx * (float)W - 0.5f);
    int iy = (int)floorf(gy * (float)H - 0.5f);
    ix = min(max(ix, 0), W - 1);
    iy = min(max(iy, 0), H - 1);
    return b * TPB + (iy / TS) * TPS + (ix / TS);
}

__global__ __launch_bounds__(256) void histo_kernel(
    const float* __restrict__ grid, int* __restrict__ cnt)
{
    __shared__ int h[NT];
    const int tid = threadIdx.x;
    for (int i = tid; i < NT; i += 256) h[i] = 0;
    __syncthreads();
    const int pt = blockIdx.x * 256 + tid;
    atomicAdd(&h[tile_of(pt, grid)], 1);
    __syncthreads();
    for (int i = tid; i < NT; i += 256) if (h[i]) atomicAdd(&cnt[i], h[i]);
}

__global__ __launch_bounds__(NT) void scan_kernel(
    const int* __restrict__ cnt, int* __restrict__ cur)
{
    __shared__ int s[NT];
    const int tid = threadIdx.x;
    const int v0 = cnt[tid];
    s[tid] = v0;
    __syncthreads();
    for (int off = 1; off < NT; off <<= 1) {
        int v = 0;
        if (tid >= off) v = s[tid - off];
        __syncthreads();
        s[tid] += v;
        __syncthreads();
    }
    cur[tid] = s[tid] - v0;                // exclusive prefix
}

__global__ __launch_bounds__(256) void scatter_kernel(
    const float* __restrict__ grid, int* __restrict__ cur, int* __restrict__ perm)
{
    const int pt = blockIdx.x * 256 + threadIdx.x;
    const int t = tile_of(pt, grid);
    const int pos = atomicAdd(&cur[t], 1);
    perm[pos] = pt;
}

__global__ __launch_bounds__(256) void point_sample_kernel(
    const float* __restrict__ features,
    const float* __restrict__ grid,
    const int* __restrict__ perm,
    float* __restrict__ out)
{
    const int wave = threadIdx.x >> 6;
    const int lane = threadIdx.x & 63;
    // XCD-chunked swizzle: 8 XCDs, each gets a contiguous chunk of the
    // bucket-ordered point list (= exactly one batch: 1024 blocks).
    int bid = blockIdx.x;
    bid = (bid & 7) * (NBLK >> 3) + (bid >> 3);
    const int w = bid * 4 + wave;

    const int4 pv = *reinterpret_cast<const int4*>(perm + w * PPW);
    const int ptv[PPW] = {pv.x, pv.y, pv.z, pv.w};
    const int c = lane * 4;

    int   off[PPW][4];
    float wgt[PPW][4];
    #pragma unroll
    for (int k = 0; k < PPW; ++k) {
        const int pt = ptv[k];
        const int b = pt >> 14;
        const float2 g = reinterpret_cast<const float2*>(grid)[pt];
        const float x = g.x * (float)W - 0.5f;
        const float y = g.y * (float)H - 0.5f;
        const float fx = floorf(x), fy = floorf(y);
        const int ix = (int)fx, iy = (int)fy;
        const float frx = x - fx, fry = y - fy;

        const int x0 = min(max(ix, 0), W - 1);
        const int x1 = min(max(ix + 1, 0), W - 1);
        const int y0 = min(max(iy, 0), H - 1);
        const int y1 = min(max(iy + 1, 0), H - 1);
        const float mx0 = (ix >= 0 && ix < W)         ? 1.f : 0.f;
        const float mx1 = (ix + 1 >= 0 && ix + 1 < W) ? 1.f : 0.f;
        const float my0 = (iy >= 0 && iy < H)         ? 1.f : 0.f;
        const float my1 = (iy + 1 >= 0 && iy + 1 < H) ? 1.f : 0.f;

        wgt[k][0] = (1.f - fry) * (1.f - frx) * my0 * mx0;
        wgt[k][1] = (1.f - fry) * frx         * my0 * mx1;
        wgt[k][2] = fry         * (1.f - frx) * my1 * mx0;
        wgt[k][3] = fry         * frx         * my1 * mx1;
        const int base = b * (H * W * C) + c;     // < 2^25, fits int
        off[k][0] = base + (y0 * W + x0) * C;
        off[k][1] = base + (y0 * W + x1) * C;
        off[k][2] = base + (y1 * W + x0) * C;
        off[k][3] = base + (y1 * W + x1) * C;
    }

    float4 v[PPW][4];
    #pragma unroll
    for (int k = 0; k < PPW; ++k)
        #pragma unroll
        for (int j = 0; j < 4; ++j)
            v[k][j] = *reinterpret_cast<const float4*>(features + off[k][j]);

    #pragma unroll
    for (int k = 0; k < PPW; ++k) {
        f32x4 acc = (f32x4)0.f;
        #pragma unroll
        for (int j = 0; j < 4; ++j) {
            const float wq = wgt[k][j];
            acc.x += wq * v[k][j].x;
            acc.y += wq * v[k][j].y;
            acc.z += wq * v[k][j].z;
            acc.w += wq * v[k][j].w;
        }
        f32x4* op = reinterpret_cast<f32x4*>(out + (size_t)ptv[k] * C + c);
        __builtin_nontemporal_store(acc, op);
    }
}

// Fallback (identity order) if workspace is too small — same math, perm-free.
__global__ __launch_bounds__(256) void point_sample_direct(
    const float* __restrict__ features,
    const float* __restrict__ grid,
    float* __restrict__ out)
{
    const int wave = threadIdx.x >> 6;
    const int lane = threadIdx.x & 63;
    const int pt = blockIdx.x * 4 + wave;
    const int b = pt >> 14;
    const float2 g = reinterpret_cast<const float2*>(grid)[pt];
    const float x = g.x * (float)W - 0.5f;
    const float y = g.y * (float)H - 0.5f;
    const float fx = floorf(x), fy = floorf(y);
    const int ix = (int)fx, iy = (int)fy;
    const float frx = x - fx, fry = y - fy;
    const float* fb = features + (size_t)b * H * W * C;
    const int c = lane * 4;
    f32x4 acc = (f32x4)0.f;
    #pragma unroll
    for (int dy = 0; dy < 2; ++dy) {
        const int hy = iy + dy;
        const bool vy = (hy >= 0) && (hy < H);
        #pragma unroll
        for (int dx = 0; dx < 2; ++dx) {
            const int wx = ix + dx;
            if (vy && (wx >= 0) && (wx < W)) {
                const float wgt = dy ? (dx ? fry * frx : fry * (1.f - frx))
                                     : (dx ? (1.f - fry) * frx : (1.f - fry) * (1.f - frx));
                const float4 vv = *reinterpret_cast<const float4*>(
                    fb + ((size_t)hy * W + wx) * C + c);
                acc.x += wgt * vv.x; acc.y += wgt * vv.y;
                acc.z += wgt * vv.z; acc.w += wgt * vv.w;
            }
        }
    }
    f32x4* op = reinterpret_cast<f32x4*>(out + (size_t)pt * C + c);
    __builtin_nontemporal_store(acc, op);
}

extern "C" void kernel_launch(void* const* d_in, const int* in_sizes, int n_in,
                              void* d_out, int out_size, void* d_ws, size_t ws_size,
                              hipStream_t stream) {
    const float* features = (const float*)d_in[0];
    const float* grid     = (const float*)d_in[1];
    float* out            = (float*)d_out;

    const size_t need = (size_t)(2 * NT + NPTS) * sizeof(int);
    if (ws_size < need) {
        point_sample_direct<<<NPTS / 4, 256, 0, stream>>>(features, grid, out);
        return;
    }

    int* cnt  = (int*)d_ws;          // NT
    int* cur  = cnt + NT;            // NT
    int* perm = cur + NT;            // NPTS

    hipMemsetAsync(cnt, 0, NT * sizeof(int), stream);
    histo_kernel  <<<NPTS / 256, 256, 0, stream>>>(grid, cnt);
    scan_kernel   <<<1, NT, 0, stream>>>(cnt, cur);
    scatter_kernel<<<NPTS / 256, 256, 0, stream>>>(grid, cur, perm);
    point_sample_kernel<<<NBLK, 256, 0, stream>>>(features, grid, perm, out);
}

// Round 6
// 56.616 us; speedup vs baseline: 2.9579x; 2.9579x over previous
//
#include <hip/hip_runtime.h>

// PointSample: bilinear grid sample, zero border.
// features: (8,128,128,256) f32, grid: (8,16384,2) f32, out: (8,16384,256) f32.
//
// Locality-bucketed: points count-sorted into 128 buckets (8 batches x 16
// tiles of 32x32 px; tile = 1 MB of features), then the main kernel walks
// points bucket-major with an XCD-chunked swizzle so each XCD streams one
// batch, one tile at a time resident in its 4 MiB L2.
// R5 lesson: global-atomic scatter (131k atomics on 128 words) serialized at
// 113 us. Now scatter aggregates ranks in LDS and does <=128 global atomics
// per block.

constexpr int B = 8, H = 128, W = 128, C = 256, P = 16384;
constexpr int PPW = 4;                  // points per wave (main kernel)
constexpr int TS = 32;                  // tile edge in pixels
constexpr int TPS = W / TS;             // 4 tiles per side
constexpr int TPB = TPS * TPS;          // 16 tiles per batch
constexpr int NT = B * TPB;             // 128 buckets
constexpr int NPTS = B * P;             // 131072 points
constexpr int NBLK = NPTS / (4 * PPW);  // 8192 main-kernel blocks

typedef float f32x4 __attribute__((ext_vector_type(4)));

__device__ __forceinline__ int tile_of(int pt, const float* grid) {
    const int b = pt >> 14;
    const float2 g = reinterpret_cast<const float2*>(grid)[pt];
    int ix = (int)floorf(g.x * (float)W - 0.5f);
    int iy = (int)floorf(g.y * (float)H - 0.5f);
    ix = min(max(ix, 0), W - 1);
    iy = min(max(iy, 0), H - 1);
    return b * TPB + (iy / TS) * TPS + (ix / TS);
}

__global__ __launch_bounds__(256) void histo_kernel(
    const float* __restrict__ grid, int* __restrict__ cnt)
{
    __shared__ int h[NT];
    const int tid = threadIdx.x;
    for (int i = tid; i < NT; i += 256) h[i] = 0;
    __syncthreads();
    const int pt = blockIdx.x * 256 + tid;
    atomicAdd(&h[tile_of(pt, grid)], 1);
    __syncthreads();
    for (int i = tid; i < NT; i += 256) if (h[i]) atomicAdd(&cnt[i], h[i]);
}

__global__ __launch_bounds__(NT) void scan_kernel(
    const int* __restrict__ cnt, int* __restrict__ cur)
{
    __shared__ int s[NT];
    const int tid = threadIdx.x;
    const int v0 = cnt[tid];
    s[tid] = v0;
    __syncthreads();
    for (int off = 1; off < NT; off <<= 1) {
        int v = 0;
        if (tid >= off) v = s[tid - off];
        __syncthreads();
        s[tid] += v;
        __syncthreads();
    }
    cur[tid] = s[tid] - v0;                // exclusive prefix
}

// LDS-aggregated scatter: local rank via shared-mem atomics, one global
// atomicAdd per (block, nonempty bucket) to reserve the range.
__global__ __launch_bounds__(256) void scatter_kernel(
    const float* __restrict__ grid, int* __restrict__ cur, int* __restrict__ perm)
{
    __shared__ int h[NT];
    __shared__ int base[NT];
    const int tid = threadIdx.x;
    for (int i = tid; i < NT; i += 256) h[i] = 0;
    __syncthreads();
    const int pt = blockIdx.x * 256 + tid;
    const int t = tile_of(pt, grid);
    const int rank = atomicAdd(&h[t], 1);          // LDS atomic
    __syncthreads();
    for (int i = tid; i < NT; i += 256)
        base[i] = h[i] ? atomicAdd(&cur[i], h[i]) : 0;
    __syncthreads();
    perm[base[t] + rank] = pt;
}

__global__ __launch_bounds__(256) void point_sample_kernel(
    const float* __restrict__ features,
    const float* __restrict__ grid,
    const int* __restrict__ perm,
    float* __restrict__ out)
{
    const int wave = threadIdx.x >> 6;
    const int lane = threadIdx.x & 63;
    // XCD-chunked swizzle: 8 XCDs, each walks a contiguous chunk of the
    // bucket-ordered point list.
    int bid = blockIdx.x;
    bid = (bid & 7) * (NBLK >> 3) + (bid >> 3);
    const int w = bid * 4 + wave;

    const int4 pv = *reinterpret_cast<const int4*>(perm + w * PPW);
    const int ptv[PPW] = {pv.x, pv.y, pv.z, pv.w};
    const int c = lane * 4;

    int   off[PPW][4];
    float wgt[PPW][4];
    #pragma unroll
    for (int k = 0; k < PPW; ++k) {
        const int pt = ptv[k];
        const int b = pt >> 14;
        const float2 g = reinterpret_cast<const float2*>(grid)[pt];
        const float x = g.x * (float)W - 0.5f;
        const float y = g.y * (float)H - 0.5f;
        const float fx = floorf(x), fy = floorf(y);
        const int ix = (int)fx, iy = (int)fy;
        const float frx = x - fx, fry = y - fy;

        const int x0 = min(max(ix, 0), W - 1);
        const int x1 = min(max(ix + 1, 0), W - 1);
        const int y0 = min(max(iy, 0), H - 1);
        const int y1 = min(max(iy + 1, 0), H - 1);
        const float mx0 = (ix >= 0 && ix < W)         ? 1.f : 0.f;
        const float mx1 = (ix + 1 >= 0 && ix + 1 < W) ? 1.f : 0.f;
        const float my0 = (iy >= 0 && iy < H)         ? 1.f : 0.f;
        const float my1 = (iy + 1 >= 0 && iy + 1 < H) ? 1.f : 0.f;

        wgt[k][0] = (1.f - fry) * (1.f - frx) * my0 * mx0;
        wgt[k][1] = (1.f - fry) * frx         * my0 * mx1;
        wgt[k][2] = fry         * (1.f - frx) * my1 * mx0;
        wgt[k][3] = fry         * frx         * my1 * mx1;
        const int fbase = b * (H * W * C) + c;     // < 2^25, fits int
        off[k][0] = fbase + (y0 * W + x0) * C;
        off[k][1] = fbase + (y0 * W + x1) * C;
        off[k][2] = fbase + (y1 * W + x0) * C;
        off[k][3] = fbase + (y1 * W + x1) * C;
    }

    float4 v[PPW][4];
    #pragma unroll
    for (int k = 0; k < PPW; ++k)
        #pragma unroll
        for (int j = 0; j < 4; ++j)
            v[k][j] = *reinterpret_cast<const float4*>(features + off[k][j]);

    #pragma unroll
    for (int k = 0; k < PPW; ++k) {
        f32x4 acc = (f32x4)0.f;
        #pragma unroll
        for (int j = 0; j < 4; ++j) {
            const float wq = wgt[k][j];
            acc.x += wq * v[k][j].x;
            acc.y += wq * v[k][j].y;
            acc.z += wq * v[k][j].z;
            acc.w += wq * v[k][j].w;
        }
        f32x4* op = reinterpret_cast<f32x4*>(out + (size_t)ptv[k] * C + c);
        __builtin_nontemporal_store(acc, op);
    }
}

// Fallback (identity order) if workspace is too small.
__global__ __launch_bounds__(256) void point_sample_direct(
    const float* __restrict__ features,
    const float* __restrict__ grid,
    float* __restrict__ out)
{
    const int wave = threadIdx.x >> 6;
    const int lane = threadIdx.x & 63;
    const int pt = blockIdx.x * 4 + wave;
    const int b = pt >> 14;
    const float2 g = reinterpret_cast<const float2*>(grid)[pt];
    const float x = g.x * (float)W - 0.5f;
    const float y = g.y * (float)H - 0.5f;
    const float fx = floorf(x), fy = floorf(y);
    const int ix = (int)fx, iy = (int)fy;
    const float frx = x - fx, fry = y - fy;
    const float* fb = features + (size_t)b * H * W * C;
    const int c = lane * 4;
    f32x4 acc = (f32x4)0.f;
    #pragma unroll
    for (int dy = 0; dy < 2; ++dy) {
        const int hy = iy + dy;
        const bool vy = (hy >= 0) && (hy < H);
        #pragma unroll
        for (int dx = 0; dx < 2; ++dx) {
            const int wx = ix + dx;
            if (vy && (wx >= 0) && (wx < W)) {
                const float wgt = dy ? (dx ? fry * frx : fry * (1.f - frx))
                                     : (dx ? (1.f - fry) * frx : (1.f - fry) * (1.f - frx));
                const float4 vv = *reinterpret_cast<const float4*>(
                    fb + ((size_t)hy * W + wx) * C + c);
                acc.x += wgt * vv.x; acc.y += wgt * vv.y;
                acc.z += wgt * vv.z; acc.w += wgt * vv.w;
            }
        }
    }
    f32x4* op = reinterpret_cast<f32x4*>(out + (size_t)pt * C + c);
    __builtin_nontemporal_store(acc, op);
}

extern "C" void kernel_launch(void* const* d_in, const int* in_sizes, int n_in,
                              void* d_out, int out_size, void* d_ws, size_t ws_size,
                              hipStream_t stream) {
    const float* features = (const float*)d_in[0];
    const float* grid     = (const float*)d_in[1];
    float* out            = (float*)d_out;

    const size_t need = (size_t)(2 * NT + NPTS) * sizeof(int);
    if (ws_size < need) {
        point_sample_direct<<<NPTS / 4, 256, 0, stream>>>(features, grid, out);
        return;
    }

    int* cnt  = (int*)d_ws;          // NT
    int* cur  = cnt + NT;            // NT
    int* perm = cur + NT;            // NPTS

    hipMemsetAsync(cnt, 0, NT * sizeof(int), stream);
    histo_kernel  <<<NPTS / 256, 256, 0, stream>>>(grid, cnt);
    scan_kernel   <<<1, NT, 0, stream>>>(cnt, cur);
    scatter_kernel<<<NPTS / 256, 256, 0, stream>>>(grid, cur, perm);
    point_sample_kernel<<<NBLK, 256, 0, stream>>>(features, grid, perm, out);
}

// Round 7
// 54.131 us; speedup vs baseline: 3.0936x; 1.0459x over previous
//
#include <hip/hip_runtime.h>

// PointSample: bilinear grid sample, zero border.
// features: (8,128,128,256) f32, grid: (8,16384,2) f32, out: (8,16384,256) f32.
//
// Locality-bucketed: points count-sorted into 128 buckets (8 batches x 16
// tiles of 32x32 px; tile = 1 MB of features), then the main kernel walks
// points bucket-major with an XCD-chunked swizzle so each XCD streams one
// batch, one tile at a time resident in its 4 MiB L2.
// R6: FETCH 222->67 MB, total 56.6 us; pre-pass chain (~19 us) now dominates
// the slack. R7: scan kernel folded into scatter (per-block local prefix of
// cnt + atomic slot reservation from zero-init off0), histo/scatter do
// 2 points/thread with float4 grid loads.

constexpr int B = 8, H = 128, W = 128, C = 256, P = 16384;
constexpr int PPW = 4;                  // points per wave (main kernel)
constexpr int TS = 32;                  // tile edge in pixels
constexpr int TPS = W / TS;             // 4 tiles per side
constexpr int TPB = TPS * TPS;          // 16 tiles per batch
constexpr int NT = B * TPB;             // 128 buckets
constexpr int NPTS = B * P;             // 131072 points
constexpr int NBLK = NPTS / (4 * PPW);  // 8192 main-kernel blocks

typedef float f32x4 __attribute__((ext_vector_type(4)));

__device__ __forceinline__ int tile_of_xy(int b, float gx, float gy) {
    int ix = (int)floorf(gx * (float)W - 0.5f);
    int iy = (int)floorf(gy * (float)H - 0.5f);
    ix = min(max(ix, 0), W - 1);
    iy = min(max(iy, 0), H - 1);
    return b * TPB + (iy / TS) * TPS + (ix / TS);
}

// 2 points per thread, float4 grid load. 256 blocks x 256 threads.
__global__ __launch_bounds__(256) void histo_kernel(
    const float* __restrict__ grid, int* __restrict__ cnt)
{
    __shared__ int h[NT];
    const int tid = threadIdx.x;
    if (tid < NT) h[tid] = 0;
    __syncthreads();
    const int pt0 = (blockIdx.x * 256 + tid) * 2;
    const float4 g = *reinterpret_cast<const float4*>(grid + (size_t)pt0 * 2);
    const int b = pt0 >> 14;                 // pair never crosses a batch
    atomicAdd(&h[tile_of_xy(b, g.x, g.y)], 1);
    atomicAdd(&h[tile_of_xy(b, g.z, g.w)], 1);
    __syncthreads();
    if (tid < NT && h[tid]) atomicAdd(&cnt[tid], h[tid]);
}

// Scatter with in-block prefix: each block recomputes the exclusive prefix
// of the (complete) global histogram, LDS-ranks its 512 points, reserves
// intra-bucket slots with one global atomic per nonempty bucket.
__global__ __launch_bounds__(256) void scatter_kernel(
    const float* __restrict__ grid, const int* __restrict__ cnt,
    int* __restrict__ off0, int* __restrict__ perm)
{
    __shared__ int h[NT];
    __shared__ int pre[NT];
    __shared__ int base[NT];
    const int tid = threadIdx.x;
    int cv = 0;
    if (tid < NT) { h[tid] = 0; cv = cnt[tid]; pre[tid] = cv; }
    __syncthreads();

    // local ranking (2 points / thread)
    const int pt0 = (blockIdx.x * 256 + tid) * 2;
    const float4 g = *reinterpret_cast<const float4*>(grid + (size_t)pt0 * 2);
    const int b = pt0 >> 14;
    const int t0 = tile_of_xy(b, g.x, g.y);
    const int t1 = tile_of_xy(b, g.z, g.w);
    const int r0 = atomicAdd(&h[t0], 1);
    const int r1 = atomicAdd(&h[t1], 1);

    // exclusive prefix of cnt (runs concurrently with ranking's barrier)
    #pragma unroll
    for (int off = 1; off < NT; off <<= 1) {
        int v = 0;
        if (tid < NT && tid >= off) v = pre[tid - off];
        __syncthreads();
        if (tid < NT) pre[tid] += v;
        __syncthreads();
    }

    if (tid < NT) {
        const int hh = h[tid];
        base[tid] = (pre[tid] - cv) + (hh ? atomicAdd(&off0[tid], hh) : 0);
    }
    __syncthreads();
    perm[base[t0] + r0] = pt0;
    perm[base[t1] + r1] = pt0 + 1;
}

__global__ __launch_bounds__(256) void point_sample_kernel(
    const float* __restrict__ features,
    const float* __restrict__ grid,
    const int* __restrict__ perm,
    float* __restrict__ out)
{
    const int wave = threadIdx.x >> 6;
    const int lane = threadIdx.x & 63;
    // XCD-chunked swizzle: each XCD walks one batch of the bucket order.
    int bid = blockIdx.x;
    bid = (bid & 7) * (NBLK >> 3) + (bid >> 3);
    const int w = bid * 4 + wave;

    const int4 pv = *reinterpret_cast<const int4*>(perm + w * PPW);
    const int ptv[PPW] = {pv.x, pv.y, pv.z, pv.w};
    const int c = lane * 4;

    int   off[PPW][4];
    float wgt[PPW][4];
    #pragma unroll
    for (int k = 0; k < PPW; ++k) {
        const int pt = ptv[k];
        const int b = pt >> 14;
        const float2 g = reinterpret_cast<const float2*>(grid)[pt];
        const float x = g.x * (float)W - 0.5f;
        const float y = g.y * (float)H - 0.5f;
        const float fx = floorf(x), fy = floorf(y);
        const int ix = (int)fx, iy = (int)fy;
        const float frx = x - fx, fry = y - fy;

        const int x0 = min(max(ix, 0), W - 1);
        const int x1 = min(max(ix + 1, 0), W - 1);
        const int y0 = min(max(iy, 0), H - 1);
        const int y1 = min(max(iy + 1, 0), H - 1);
        const float mx0 = (ix >= 0 && ix < W)         ? 1.f : 0.f;
        const float mx1 = (ix + 1 >= 0 && ix + 1 < W) ? 1.f : 0.f;
        const float my0 = (iy >= 0 && iy < H)         ? 1.f : 0.f;
        const float my1 = (iy + 1 >= 0 && iy + 1 < H) ? 1.f : 0.f;

        wgt[k][0] = (1.f - fry) * (1.f - frx) * my0 * mx0;
        wgt[k][1] = (1.f - fry) * frx         * my0 * mx1;
        wgt[k][2] = fry         * (1.f - frx) * my1 * mx0;
        wgt[k][3] = fry         * frx         * my1 * mx1;
        const int fbase = b * (H * W * C) + c;     // < 2^25, fits int
        off[k][0] = fbase + (y0 * W + x0) * C;
        off[k][1] = fbase + (y0 * W + x1) * C;
        off[k][2] = fbase + (y1 * W + x0) * C;
        off[k][3] = fbase + (y1 * W + x1) * C;
    }

    float4 v[PPW][4];
    #pragma unroll
    for (int k = 0; k < PPW; ++k)
        #pragma unroll
        for (int j = 0; j < 4; ++j)
            v[k][j] = *reinterpret_cast<const float4*>(features + off[k][j]);

    #pragma unroll
    for (int k = 0; k < PPW; ++k) {
        f32x4 acc = (f32x4)0.f;
        #pragma unroll
        for (int j = 0; j < 4; ++j) {
            const float wq = wgt[k][j];
            acc.x += wq * v[k][j].x;
            acc.y += wq * v[k][j].y;
            acc.z += wq * v[k][j].z;
            acc.w += wq * v[k][j].w;
        }
        f32x4* op = reinterpret_cast<f32x4*>(out + (size_t)ptv[k] * C + c);
        __builtin_nontemporal_store(acc, op);
    }
}

// Fallback (identity order) if workspace is too small.
__global__ __launch_bounds__(256) void point_sample_direct(
    const float* __restrict__ features,
    const float* __restrict__ grid,
    float* __restrict__ out)
{
    const int wave = threadIdx.x >> 6;
    const int lane = threadIdx.x & 63;
    const int pt = blockIdx.x * 4 + wave;
    const int b = pt >> 14;
    const float2 g = reinterpret_cast<const float2*>(grid)[pt];
    const float x = g.x * (float)W - 0.5f;
    const float y = g.y * (float)H - 0.5f;
    const float fx = floorf(x), fy = floorf(y);
    const int ix = (int)fx, iy = (int)fy;
    const float frx = x - fx, fry = y - fy;
    const float* fb = features + (size_t)b * H * W * C;
    const int c = lane * 4;
    f32x4 acc = (f32x4)0.f;
    #pragma unroll
    for (int dy = 0; dy < 2; ++dy) {
        const int hy = iy + dy;
        const bool vy = (hy >= 0) && (hy < H);
        #pragma unroll
        for (int dx = 0; dx < 2; ++dx) {
            const int wx = ix + dx;
            if (vy && (wx >= 0) && (wx < W)) {
                const float wgt = dy ? (dx ? fry * frx : fry * (1.f - frx))
                                     : (dx ? (1.f - fry) * frx : (1.f - fry) * (1.f - frx));
                const float4 vv = *reinterpret_cast<const float4*>(
                    fb + ((size_t)hy * W + wx) * C + c);
                acc.x += wgt * vv.x; acc.y += wgt * vv.y;
                acc.z += wgt * vv.z; acc.w += wgt * vv.w;
            }
        }
    }
    f32x4* op = reinterpret_cast<f32x4*>(out + (size_t)pt * C + c);
    __builtin_nontemporal_store(acc, op);
}

extern "C" void kernel_launch(void* const* d_in, const int* in_sizes, int n_in,
                              void* d_out, int out_size, void* d_ws, size_t ws_size,
                              hipStream_t stream) {
    const float* features = (const float*)d_in[0];
    const float* grid     = (const float*)d_in[1];
    float* out            = (float*)d_out;

    const size_t need = (size_t)(2 * NT + NPTS) * sizeof(int);
    if (ws_size < need) {
        point_sample_direct<<<NPTS / 4, 256, 0, stream>>>(features, grid, out);
        return;
    }

    int* cnt  = (int*)d_ws;          // NT
    int* off0 = cnt + NT;            // NT
    int* perm = off0 + NT;           // NPTS

    hipMemsetAsync(cnt, 0, 2 * NT * sizeof(int), stream);   // cnt + off0
    histo_kernel  <<<NPTS / 512, 256, 0, stream>>>(grid, cnt);
    scatter_kernel<<<NPTS / 512, 256, 0, stream>>>(grid, cnt, off0, perm);
    point_sample_kernel<<<NBLK, 256, 0, stream>>>(features, grid, perm, out);
}